// Round 1
// baseline (773.378 us; speedup 1.0000x reference)
//
#include <hip/hip_runtime.h>
#include <stdint.h>
#include <stddef.h>

#define C_DIM 248
#define N_KP 512
#define HW_PIX 65536
#define NWIN 4
#define NCHUNK 32
#define CHUNK_PIX 2048
#define NTILE 32            // CHUNK_PIX / 64
#define TEMP_SCALE 100.0f   // 1 / SOFTMAX_TEMP

typedef __attribute__((ext_vector_type(8))) short bf16x8;
typedef __attribute__((ext_vector_type(4))) float f32x4;

__device__ __forceinline__ unsigned short f32_bf16(float f) {
    union { float f; uint32_t u; } x; x.f = f;
    uint32_t r = x.u + 0x7FFFu + ((x.u >> 16) & 1u);
    return (unsigned short)(r >> 16);
}
__device__ __forceinline__ float bf16_f32(unsigned short h) {
    union { uint32_t u; float f; } x; x.u = ((uint32_t)h) << 16;
    return x.f;
}

// ---------------- Kernel 1: per-pixel 100/||src column|| ----------------
__global__ __launch_bounds__(256) void k_norms(const float* __restrict__ dd,
                                               float* __restrict__ scale) {
    int flat = blockIdx.x * 256 + threadIdx.x;   // [0, 4*65536)
    int b = flat >> 16;
    int h = flat & 65535;
    const float* p = dd + (size_t)(2 * b) * C_DIM * HW_PIX + h;
    float ss = 0.0f;
    #pragma unroll 8
    for (int c = 0; c < C_DIM; ++c) {
        float v = p[(size_t)c * HW_PIX];
        ss = fmaf(v, v, ss);
    }
    float nrm = sqrtf(ss);
    scale[flat] = TEMP_SCALE / fmaxf(nrm, 1e-12f);
}

// ---------------- Kernel 2: fused split-bf16 MFMA + online softmax ----------------
// grid: 4 windows x 8 mtiles x 32 chunks; block: 256 threads (4 waves)
// wave w owns keypoint rows [mtile*64 + w*16, +16); output tile 16x64 pixels/iter
__global__ __launch_bounds__(256) void k_main(const float* __restrict__ dd,
                                              const float* __restrict__ kd,
                                              const float* __restrict__ scale,
                                              float4* __restrict__ partials) {
    int bid = blockIdx.x;
    int mtile = bid & 7;
    int chunk = (bid >> 3) & 31;
    int b = bid >> 8;
    int tid = threadIdx.x;
    int lane = tid & 63;
    int wave = tid >> 6;
    int l15 = lane & 15;
    int l4 = lane >> 4;

    // [h][k] with +8 short padding: b128 reads stay 16B-aligned, ~2-way banks
    __shared__ __align__(16) unsigned short Bh[64][72];
    __shared__ __align__(16) unsigned short Bl[64][72];

    // --- A fragments: 16 keypoint rows per wave, K padded to 256 ---
    const float* tgtp = kd + (size_t)(2 * b + 1) * C_DIM * N_KP;
    int n_g = mtile * 64 + wave * 16 + l15;
    bf16x8 aH[8], aL[8];
    #pragma unroll
    for (int ks = 0; ks < 8; ++ks) {
        #pragma unroll
        for (int j = 0; j < 8; ++j) {
            int c = ks * 32 + l4 * 8 + j;
            float v = (c < C_DIM) ? tgtp[(size_t)c * N_KP + n_g] : 0.0f;
            unsigned short hb = f32_bf16(v);
            float lo = v - bf16_f32(hb);
            aH[ks][j] = (short)hb;
            aL[ks][j] = (short)f32_bf16(lo);
        }
    }

    float mrun[4], drun[4], sxr[4], syr[4];
    #pragma unroll
    for (int r = 0; r < 4; ++r) { mrun[r] = -1e30f; drun[r] = 0.f; sxr[r] = 0.f; syr[r] = 0.f; }

    const float* srcp = dd + (size_t)(2 * b) * C_DIM * HW_PIX;
    const float* scp  = scale + (size_t)b * HW_PIX;
    int hchunk = chunk * CHUNK_PIX;

    for (int t = 0; t < NTILE; ++t) {
        int h0 = hchunk + t * 64;
        f32x4 acc[4];
        #pragma unroll
        for (int s = 0; s < 4; ++s) acc[s] = (f32x4){0.f, 0.f, 0.f, 0.f};

        #pragma unroll
        for (int s = 0; s < 4; ++s) {           // K slices of 64
            __syncthreads();
            // stage fp32 -> bf16 hi/lo into LDS (64 k-rows x 64 pixels)
            #pragma unroll
            for (int i = 0; i < 4; ++i) {
                int idx = tid + 256 * i;        // 0..1023
                int krow = idx >> 4;            // 0..63
                int h4 = (idx & 15) * 4;        // 0,4,..,60
                int c = s * 64 + krow;
                float4 v = {0.f, 0.f, 0.f, 0.f};
                if (c < C_DIM) v = *(const float4*)(srcp + (size_t)c * HW_PIX + h0 + h4);
                #pragma unroll
                for (int m = 0; m < 4; ++m) {
                    float f = (&v.x)[m];
                    unsigned short hb = f32_bf16(f);
                    float lo = f - bf16_f32(hb);
                    Bh[h4 + m][krow] = hb;
                    Bl[h4 + m][krow] = f32_bf16(lo);
                }
            }
            __syncthreads();
            #pragma unroll
            for (int ks32 = 0; ks32 < 2; ++ks32) {
                int kk = s * 2 + ks32;
                #pragma unroll
                for (int sub = 0; sub < 4; ++sub) {
                    const bf16x8 bH = *(const bf16x8*)&Bh[sub * 16 + l15][ks32 * 32 + l4 * 8];
                    const bf16x8 bL = *(const bf16x8*)&Bl[sub * 16 + l15][ks32 * 32 + l4 * 8];
                    acc[sub] = __builtin_amdgcn_mfma_f32_16x16x32_bf16(aH[kk], bH, acc[sub], 0, 0, 0);
                    acc[sub] = __builtin_amdgcn_mfma_f32_16x16x32_bf16(aH[kk], bL, acc[sub], 0, 0, 0);
                    acc[sub] = __builtin_amdgcn_mfma_f32_16x16x32_bf16(aL[kk], bH, acc[sub], 0, 0, 0);
                }
            }
        }

        // ---- logits + online softmax update ----
        // D layout: col = lane&15 (pixel), row = (lane>>4)*4 + reg (keypoint)
        float lg[4][4];
        float tmax[4];
        #pragma unroll
        for (int r = 0; r < 4; ++r) tmax[r] = -1e30f;
        #pragma unroll
        for (int sub = 0; sub < 4; ++sub) {
            float sc = scp[h0 + sub * 16 + l15];
            #pragma unroll
            for (int r = 0; r < 4; ++r) {
                lg[sub][r] = acc[sub][r] * sc;
                tmax[r] = fmaxf(tmax[r], lg[sub][r]);
            }
        }
        #pragma unroll
        for (int off = 1; off <= 8; off <<= 1) {
            #pragma unroll
            for (int r = 0; r < 4; ++r)
                tmax[r] = fmaxf(tmax[r], __shfl_xor(tmax[r], off));
        }
        #pragma unroll
        for (int r = 0; r < 4; ++r) {
            float Mn = fmaxf(mrun[r], tmax[r]);
            float corr = __expf(mrun[r] - Mn);
            drun[r] *= corr; sxr[r] *= corr; syr[r] *= corr;
            mrun[r] = Mn;
        }
        #pragma unroll
        for (int sub = 0; sub < 4; ++sub) {
            int h = h0 + sub * 16 + l15;
            float u = (float)(h & 255);
            float vv = (float)(h >> 8);
            #pragma unroll
            for (int r = 0; r < 4; ++r) {
                float e = __expf(lg[sub][r] - mrun[r]);
                drun[r] += e;
                sxr[r] = fmaf(e, u, sxr[r]);
                syr[r] = fmaf(e, vv, syr[r]);
            }
        }
    }

    // ---- reduce the 16 column-lanes of each row group, write partials ----
    #pragma unroll
    for (int off = 1; off <= 8; off <<= 1) {
        #pragma unroll
        for (int r = 0; r < 4; ++r) {
            drun[r] += __shfl_xor(drun[r], off);
            sxr[r]  += __shfl_xor(sxr[r], off);
            syr[r]  += __shfl_xor(syr[r], off);
        }
    }
    if (l15 == 0) {
        #pragma unroll
        for (int r = 0; r < 4; ++r) {
            int n = mtile * 64 + wave * 16 + l4 * 4 + r;
            float4 p; p.x = mrun[r]; p.y = drun[r]; p.z = sxr[r]; p.w = syr[r];
            partials[((size_t)b * N_KP + n) * NCHUNK + chunk] = p;
        }
    }
}

// ---------------- Kernel 3: combine chunk partials + epilogue outputs ----------------
__global__ __launch_bounds__(256) void k_reduce(const float4* __restrict__ partials,
                                                const float* __restrict__ ksc,
                                                float* __restrict__ out) {
    int flat = blockIdx.x * 256 + threadIdx.x;   // 0..2047 = b*512 + n
    int b = flat >> 9;
    int n = flat & 511;
    float M = -1e30f, D = 0.f, SX = 0.f, SY = 0.f;
    for (int c = 0; c < NCHUNK; ++c) {
        float4 p = partials[(size_t)flat * NCHUNK + c];
        float Mn = fmaxf(M, p.x);
        float corr = __expf(M - Mn);
        float w = __expf(p.x - Mn);
        D  = D  * corr + p.y * w;
        SX = SX * corr + p.z * w;
        SY = SY * corr + p.w * w;
        M = Mn;
    }
    out[flat * 2 + 0] = SX / D;
    out[flat * 2 + 1] = SY / D;
    out[4096 + flat] = ksc[(size_t)(2 * b + 1) * N_KP + n];
    if (flat < 4) out[6144 + flat] = (float)(2 * flat + 1);
}

extern "C" void kernel_launch(void* const* d_in, const int* in_sizes, int n_in,
                              void* d_out, int out_size, void* d_ws, size_t ws_size,
                              hipStream_t stream) {
    const float* kp_scores  = (const float*)d_in[0];
    const float* kp_desc    = (const float*)d_in[1];
    // d_in[2] (scores_dense) is unused by the reference
    const float* desc_dense = (const float*)d_in[3];
    float* out = (float*)d_out;

    float* scale = (float*)d_ws;                               // 4*65536 floats = 1 MB
    float4* partials = (float4*)(scale + (size_t)NWIN * HW_PIX); // 4*512*32 float4 = 1 MB

    k_norms<<<NWIN * HW_PIX / 256, 256, 0, stream>>>(desc_dense, scale);
    k_main<<<NWIN * 8 * NCHUNK, 256, 0, stream>>>(desc_dense, kp_desc, scale, partials);
    k_reduce<<<8, 256, 0, stream>>>(partials, kp_scores, out);
}

// Round 2
// 546.905 us; speedup vs baseline: 1.4141x; 1.4141x over previous
//
#include <hip/hip_runtime.h>
#include <stdint.h>
#include <stddef.h>

#define C_DIM 248
#define N_KP 512
#define HW_PIX 65536
#define NWIN 4
#define NKK 8              // K slices of 32 (K padded to 256)
#define NTILE_N 32         // 512 keypoints / 16
#define GROUPS 1024        // 64-pixel groups per window
#define TEMP_SCALE 100.0f

typedef __attribute__((ext_vector_type(8))) short bf16x8;
typedef __attribute__((ext_vector_type(4))) float f32x4;

__device__ __forceinline__ unsigned short f32_bf16(float f) {
    union { float f; uint32_t u; } x; x.f = f;
    uint32_t r = x.u + 0x7FFFu + ((x.u >> 16) & 1u);
    return (unsigned short)(r >> 16);
}
__device__ __forceinline__ float bf16_f32(unsigned short h) {
    union { uint32_t u; float f; } x; x.u = ((uint32_t)h) << 16;
    return x.f;
}

// ---------- Kernel 1: keypoint desc -> fragment-ordered bf16 hi/lo ----------
// Layout: Bp[(((b*8+kk)*512+col)*4 + l4)] = 8 shorts for k = kk*32 + l4*8 + j
__global__ __launch_bounds__(256) void k_prep(const float* __restrict__ kd,
                                              bf16x8* __restrict__ Bph,
                                              bf16x8* __restrict__ Bpl) {
    int g = blockIdx.x * 256 + threadIdx.x;       // 65536 threads
    int col = g & 511;
    int rest = g >> 9;
    int l4 = rest & 3;
    int kk = (rest >> 2) & 7;
    int b = rest >> 5;
    const float* base = kd + (size_t)(2 * b + 1) * C_DIM * N_KP;
    bf16x8 hi, lo;
    #pragma unroll
    for (int j = 0; j < 8; ++j) {
        int c = kk * 32 + l4 * 8 + j;
        float v = (c < C_DIM) ? base[(size_t)c * N_KP + col] : 0.0f;
        unsigned short hb = f32_bf16(v);
        float rlo = v - bf16_f32(hb);
        hi[j] = (short)hb;
        lo[j] = (short)f32_bf16(rlo);
    }
    int idx = ((b * 8 + kk) * 512 + col) * 4 + l4;
    Bph[idx] = hi;
    Bpl[idx] = lo;
}

// ---------- Kernel 2: A-in-registers MFMA + per-group softmax partials ----------
// grid: 4 windows x 1024 groups (64 pixels); block: 256 threads (4 waves x 16 px)
__global__ __launch_bounds__(256) void k_main(const float* __restrict__ dd,
                                              const bf16x8* __restrict__ Bph,
                                              const bf16x8* __restrict__ Bpl,
                                              float4* __restrict__ partials) {
    int b = blockIdx.x >> 10;
    int grp = blockIdx.x & 1023;
    int tid = threadIdx.x;
    int lane = tid & 63;
    int wave = tid >> 6;
    int l15 = lane & 15;
    int l4 = lane >> 4;
    int pw = grp * 64 + wave * 16;                // wave's first pixel

    __shared__ float4 Wst[4][512];                // per-wave kp partials (32 KB)

    // ---- load A (16 pixels x 256 k) into registers, hi/lo split; fused norm ----
    const float* srcp = dd + (size_t)(2 * b) * C_DIM * HW_PIX;
    bf16x8 aH[8], aL[8];
    float ss = 0.0f;
    #pragma unroll
    for (int kk = 0; kk < 8; ++kk) {
        #pragma unroll
        for (int j = 0; j < 8; ++j) {
            int c = kk * 32 + l4 * 8 + j;
            float v = (c < C_DIM) ? srcp[(size_t)c * HW_PIX + pw + l15] : 0.0f;
            ss = fmaf(v, v, ss);
            unsigned short hb = f32_bf16(v);
            float rlo = v - bf16_f32(hb);
            aH[kk][j] = (short)hb;
            aL[kk][j] = (short)f32_bf16(rlo);
        }
    }
    // full per-pixel sum of squares (combine the 4 l4 copies)
    ss += __shfl_xor(ss, 16);
    ss += __shfl_xor(ss, 32);
    // redistribute to D-layout rows: row r of this lane is pixel pw + l4*4 + r
    float srow[4], uu[4], vv[4];
    #pragma unroll
    for (int r = 0; r < 4; ++r) {
        float ssr = __shfl(ss, l4 * 4 + r);       // lane id l4*4+r has l15 == l4*4+r
        srow[r] = TEMP_SCALE / fmaxf(sqrtf(ssr), 1e-12f);
        int pix = pw + l4 * 4 + r;
        uu[r] = (float)(pix & 255);
        vv[r] = (float)(pix >> 8);
    }

    // ---- loop over keypoint tiles ----
    for (int t = 0; t < NTILE_N; ++t) {
        int col = t * 16 + l15;
        f32x4 a0 = (f32x4){0.f, 0.f, 0.f, 0.f};
        f32x4 a1 = (f32x4){0.f, 0.f, 0.f, 0.f};
        f32x4 a2 = (f32x4){0.f, 0.f, 0.f, 0.f};
        #pragma unroll
        for (int kk = 0; kk < 8; ++kk) {
            int idx = (((b << 3) + kk) << 9 | col) << 2 | l4;
            bf16x8 bH = Bph[idx];
            bf16x8 bL = Bpl[idx];
            a0 = __builtin_amdgcn_mfma_f32_16x16x32_bf16(aH[kk], bH, a0, 0, 0, 0);
            a1 = __builtin_amdgcn_mfma_f32_16x16x32_bf16(aH[kk], bL, a1, 0, 0, 0);
            a2 = __builtin_amdgcn_mfma_f32_16x16x32_bf16(aL[kk], bH, a2, 0, 0, 0);
        }
        // logits for 16 pixels x 16 kp; reduce over pixels (rows)
        float lg[4];
        float tm = -1e30f;
        #pragma unroll
        for (int r = 0; r < 4; ++r) {
            lg[r] = (a0[r] + a1[r] + a2[r]) * srow[r];
            tm = fmaxf(tm, lg[r]);
        }
        tm = fmaxf(tm, __shfl_xor(tm, 16));
        tm = fmaxf(tm, __shfl_xor(tm, 32));       // col-max over all 16 pixels
        float d = 0.f, sx = 0.f, sy = 0.f;
        #pragma unroll
        for (int r = 0; r < 4; ++r) {
            float e = __expf(lg[r] - tm);
            d += e;
            sx = fmaf(e, uu[r], sx);
            sy = fmaf(e, vv[r], sy);
        }
        d += __shfl_xor(d, 16);  d += __shfl_xor(d, 32);
        sx += __shfl_xor(sx, 16); sx += __shfl_xor(sx, 32);
        sy += __shfl_xor(sy, 16); sy += __shfl_xor(sy, 32);
        if (l4 == 0) {
            float4 p; p.x = tm; p.y = d; p.z = sx; p.w = sy;
            Wst[wave][col] = p;
        }
    }

    // ---- combine 4 waves' partials (64 pixels), write one partial per kp ----
    __syncthreads();
    for (int idx = tid; idx < 512; idx += 256) {
        float4 s = Wst[0][idx];
        float M = s.x, D = s.y, SX = s.z, SY = s.w;
        #pragma unroll
        for (int w = 1; w < 4; ++w) {
            float4 p = Wst[w][idx];
            float Mn = fmaxf(M, p.x);
            float c1 = __expf(M - Mn);
            float c2 = __expf(p.x - Mn);
            D  = D  * c1 + p.y * c2;
            SX = SX * c1 + p.z * c2;
            SY = SY * c1 + p.w * c2;
            M = Mn;
        }
        float4 o; o.x = M; o.y = D; o.z = SX; o.w = SY;
        partials[((size_t)b * GROUPS + grp) * 512 + idx] = o;
    }
}

// ---------- Kernel 3: reduce 1024 group-partials per (b,kp) + epilogue ----------
// grid: 4 windows x 32 kp-chunks of 16; block 256 = 16 kp x 16 g-slices
__global__ __launch_bounds__(256) void k_reduce(const float4* __restrict__ partials,
                                                const float* __restrict__ ksc,
                                                float* __restrict__ out) {
    int b = blockIdx.x >> 5;
    int kc = blockIdx.x & 31;
    int tid = threadIdx.x;
    int kpo = tid & 15;
    int gs = tid >> 4;
    int kp = kc * 16 + kpo;

    float M = -1e30f, D = 0.f, SX = 0.f, SY = 0.f;
    for (int g = gs; g < GROUPS; g += 16) {
        float4 p = partials[((size_t)b * GROUPS + g) * 512 + kp];
        float Mn = fmaxf(M, p.x);
        float c1 = __expf(M - Mn);
        float c2 = __expf(p.x - Mn);
        D  = D  * c1 + p.y * c2;
        SX = SX * c1 + p.z * c2;
        SY = SY * c1 + p.w * c2;
        M = Mn;
    }
    __shared__ float4 red[16][16];
    float4 me; me.x = M; me.y = D; me.z = SX; me.w = SY;
    red[gs][kpo] = me;
    __syncthreads();
    if (gs == 0) {
        #pragma unroll
        for (int w = 1; w < 16; ++w) {
            float4 p = red[w][kpo];
            float Mn = fmaxf(M, p.x);
            float c1 = __expf(M - Mn);
            float c2 = __expf(p.x - Mn);
            D  = D  * c1 + p.y * c2;
            SX = SX * c1 + p.z * c2;
            SY = SY * c1 + p.w * c2;
            M = Mn;
        }
        int flat = b * 512 + kp;
        out[flat * 2 + 0] = SX / D;
        out[flat * 2 + 1] = SY / D;
        out[4096 + flat] = ksc[(size_t)(2 * b + 1) * N_KP + kp];
    }
    if (blockIdx.x == 0 && tid < 4) out[6144 + tid] = (float)(2 * tid + 1);
}

extern "C" void kernel_launch(void* const* d_in, const int* in_sizes, int n_in,
                              void* d_out, int out_size, void* d_ws, size_t ws_size,
                              hipStream_t stream) {
    const float* kp_scores  = (const float*)d_in[0];
    const float* kp_desc    = (const float*)d_in[1];
    const float* desc_dense = (const float*)d_in[3];
    float* out = (float*)d_out;

    // ws layout: Bph (1 MB) | Bpl (1 MB) | partials (32 MB)
    bf16x8* Bph = (bf16x8*)d_ws;
    bf16x8* Bpl = Bph + (size_t)NWIN * 8 * 512 * 4;
    float4* partials = (float4*)(Bpl + (size_t)NWIN * 8 * 512 * 4);

    k_prep<<<256, 256, 0, stream>>>(kp_desc, Bph, Bpl);
    k_main<<<NWIN * GROUPS, 256, 0, stream>>>(desc_dense, Bph, Bpl, partials);
    k_reduce<<<NWIN * 32, 256, 0, stream>>>(partials, kp_scores, out);
}

// Round 3
// 538.769 us; speedup vs baseline: 1.4355x; 1.0151x over previous
//
#include <hip/hip_runtime.h>
#include <stdint.h>
#include <stddef.h>

#define C_DIM 248
#define N_KP 512
#define HW_PIX 65536
#define NWIN 4
#define NTILE_N 32         // 512 keypoints / 16
#define GROUPS 1024        // 64-pixel groups per window
#define TEMP_SCALE 100.0f

typedef __attribute__((ext_vector_type(8))) short bf16x8;
typedef __attribute__((ext_vector_type(4))) float f32x4;

__device__ __forceinline__ unsigned short f32_bf16(float f) {
    union { float f; uint32_t u; } x; x.f = f;
    uint32_t r = x.u + 0x7FFFu + ((x.u >> 16) & 1u);
    return (unsigned short)(r >> 16);
}
__device__ __forceinline__ float bf16_f32(unsigned short h) {
    union { uint32_t u; float f; } x; x.u = ((uint32_t)h) << 16;
    return x.f;
}

// ---------- Kernel 1: keypoint desc -> fragment-ordered bf16 hi/lo ----------
// Bp[(((b*8+kk)*512+col)*4 + l4)] = 8 shorts for k = kk*32 + l4*8 + j
__global__ __launch_bounds__(256) void k_prep(const float* __restrict__ kd,
                                              bf16x8* __restrict__ Bph,
                                              bf16x8* __restrict__ Bpl) {
    int g = blockIdx.x * 256 + threadIdx.x;       // 65536 threads
    int col = g & 511;
    int rest = g >> 9;
    int l4 = rest & 3;
    int kk = (rest >> 2) & 7;
    int b = rest >> 5;
    const float* base = kd + (size_t)(2 * b + 1) * C_DIM * N_KP;
    bf16x8 hi, lo;
    #pragma unroll
    for (int j = 0; j < 8; ++j) {
        int c = kk * 32 + l4 * 8 + j;
        float v = (c < C_DIM) ? base[(size_t)c * N_KP + col] : 0.0f;
        unsigned short hb = f32_bf16(v);
        float rlo = v - bf16_f32(hb);
        hi[j] = (short)hb;
        lo[j] = (short)f32_bf16(rlo);
    }
    int idx = ((b * 8 + kk) * 512 + col) * 4 + l4;
    Bph[idx] = hi;
    Bpl[idx] = lo;
}

// ---------- Kernel 2: A-in-registers MFMA, zero-shuffle softmax ----------
// grid: 4 windows x 1024 groups (64 px); block: 256 threads (4 waves x 16 px)
__global__ __launch_bounds__(256, 3) void k_main(const float* __restrict__ dd,
                                                 const bf16x8* __restrict__ Bph,
                                                 const bf16x8* __restrict__ Bpl,
                                                 float4* __restrict__ partials) {
    int b = blockIdx.x >> 10;
    int grp = blockIdx.x & 1023;
    int tid = threadIdx.x;
    int lane = tid & 63;
    int wave = tid >> 6;
    int l15 = lane & 15;
    int l4 = lane >> 4;
    int pw = grp * 64 + wave * 16;

    // [wave][l4][col within 8-tile chunk] partials (32 KB)
    __shared__ float4 Wst[4][4][128];

    // ---- A: 16 px x 256 k in registers (hi/lo), fused norm ----
    const float* srcp = dd + (size_t)(2 * b) * C_DIM * HW_PIX;
    bf16x8 aH[8], aL[8];
    float ss = 0.0f;
    #pragma unroll
    for (int kk = 0; kk < 8; ++kk) {
        #pragma unroll
        for (int j = 0; j < 8; ++j) {
            int c = kk * 32 + l4 * 8 + j;
            float v = (c < C_DIM) ? srcp[(size_t)c * HW_PIX + pw + l15] : 0.0f;
            ss = fmaf(v, v, ss);
            unsigned short hb = f32_bf16(v);
            float rlo = v - bf16_f32(hb);
            aH[kk][j] = (short)hb;
            aL[kk][j] = (short)f32_bf16(rlo);
        }
    }
    ss += __shfl_xor(ss, 16);
    ss += __shfl_xor(ss, 32);                      // full 248-sum, pixel pw+l15
    float srow[4], uu[4], vv[4];
    #pragma unroll
    for (int r = 0; r < 4; ++r) {
        float ssr = __shfl(ss, l4 * 4 + r);        // lane i<16 holds pixel pw+i
        srow[r] = TEMP_SCALE / fmaxf(sqrtf(ssr), 1e-12f);
        int pix = pw + l4 * 4 + r;
        uu[r] = (float)(pix & 255);
        vv[r] = (float)(pix >> 8);
    }

    // ---- keypoint tiles: 4 chunks x 8 tiles ----
    for (int tc = 0; tc < 4; ++tc) {
        #pragma unroll 1
        for (int tt = 0; tt < 8; ++tt) {
            int t = tc * 8 + tt;
            int col = t * 16 + l15;
            // hoist ALL B loads for this tile (16 x 16B, one batch)
            bf16x8 bH[8], bL[8];
            #pragma unroll
            for (int kk = 0; kk < 8; ++kk) {
                int idx = (((b << 3) + kk) << 9 | col) << 2 | l4;
                bH[kk] = Bph[idx];
                bL[kk] = Bpl[idx];
            }
            f32x4 a0 = (f32x4){0.f, 0.f, 0.f, 0.f};
            f32x4 a1 = (f32x4){0.f, 0.f, 0.f, 0.f};
            f32x4 a2 = (f32x4){0.f, 0.f, 0.f, 0.f};
            #pragma unroll
            for (int kk = 0; kk < 8; ++kk) {
                a0 = __builtin_amdgcn_mfma_f32_16x16x32_bf16(aH[kk], bH[kk], a0, 0, 0, 0);
                a1 = __builtin_amdgcn_mfma_f32_16x16x32_bf16(aH[kk], bL[kk], a1, 0, 0, 0);
                a2 = __builtin_amdgcn_mfma_f32_16x16x32_bf16(aL[kk], bH[kk], a2, 0, 0, 0);
            }
            // per-lane (4-row) local softmax partial: NO cross-lane ops
            float lg[4];
            float m = -3.0e38f;
            #pragma unroll
            for (int r = 0; r < 4; ++r) {
                lg[r] = (a0[r] + a1[r] + a2[r]) * srow[r];
                m = fmaxf(m, lg[r]);
            }
            float d = 0.f, sx = 0.f, sy = 0.f;
            #pragma unroll
            for (int r = 0; r < 4; ++r) {
                float e = __expf(lg[r] - m);
                d += e;
                sx = fmaf(e, uu[r], sx);
                sy = fmaf(e, vv[r], sy);
            }
            float4 p; p.x = m; p.y = d; p.z = sx; p.w = sy;
            Wst[wave][l4][tt * 16 + l15] = p;
        }
        __syncthreads();
        if (tid < 128) {
            float4 s = Wst[0][0][tid];
            float M = s.x, D = s.y, SX = s.z, SY = s.w;
            #pragma unroll
            for (int sIdx = 1; sIdx < 16; ++sIdx) {
                float4 p = Wst[sIdx >> 2][sIdx & 3][tid];
                float Mn = fmaxf(M, p.x);
                float c1 = __expf(M - Mn);
                float c2 = __expf(p.x - Mn);
                D  = D  * c1 + p.y * c2;
                SX = SX * c1 + p.z * c2;
                SY = SY * c1 + p.w * c2;
                M = Mn;
            }
            float4 o; o.x = M; o.y = D; o.z = SX; o.w = SY;
            partials[((size_t)b * GROUPS + grp) * 512 + tc * 128 + tid] = o;
        }
        __syncthreads();
    }
}

// ---------- Kernel 3: reduce 1024 group-partials per (b,kp) + epilogue ----------
__global__ __launch_bounds__(256) void k_reduce(const float4* __restrict__ partials,
                                                const float* __restrict__ ksc,
                                                float* __restrict__ out) {
    int b = blockIdx.x >> 5;
    int kc = blockIdx.x & 31;
    int tid = threadIdx.x;
    int kpo = tid & 15;
    int gs = tid >> 4;
    int kp = kc * 16 + kpo;

    float M = -1e30f, D = 0.f, SX = 0.f, SY = 0.f;
    for (int g = gs; g < GROUPS; g += 16) {
        float4 p = partials[((size_t)b * GROUPS + g) * 512 + kp];
        float Mn = fmaxf(M, p.x);
        float c1 = __expf(M - Mn);
        float c2 = __expf(p.x - Mn);
        D  = D  * c1 + p.y * c2;
        SX = SX * c1 + p.z * c2;
        SY = SY * c1 + p.w * c2;
        M = Mn;
    }
    __shared__ float4 red[16][16];
    float4 me; me.x = M; me.y = D; me.z = SX; me.w = SY;
    red[gs][kpo] = me;
    __syncthreads();
    if (gs == 0) {
        #pragma unroll
        for (int w = 1; w < 16; ++w) {
            float4 p = red[w][kpo];
            float Mn = fmaxf(M, p.x);
            float c1 = __expf(M - Mn);
            float c2 = __expf(p.x - Mn);
            D  = D  * c1 + p.y * c2;
            SX = SX * c1 + p.z * c2;
            SY = SY * c1 + p.w * c2;
            M = Mn;
        }
        int flat = b * 512 + kp;
        out[flat * 2 + 0] = SX / D;
        out[flat * 2 + 1] = SY / D;
        out[4096 + flat] = ksc[(size_t)(2 * b + 1) * N_KP + kp];
    }
    if (blockIdx.x == 0 && tid < 4) out[6144 + tid] = (float)(2 * tid + 1);
}

extern "C" void kernel_launch(void* const* d_in, const int* in_sizes, int n_in,
                              void* d_out, int out_size, void* d_ws, size_t ws_size,
                              hipStream_t stream) {
    const float* kp_scores  = (const float*)d_in[0];
    const float* kp_desc    = (const float*)d_in[1];
    const float* desc_dense = (const float*)d_in[3];
    float* out = (float*)d_out;

    // ws layout: Bph (1 MB) | Bpl (1 MB) | partials (32 MB)
    bf16x8* Bph = (bf16x8*)d_ws;
    bf16x8* Bpl = Bph + (size_t)NWIN * 8 * 512 * 4;
    float4* partials = (float4*)(Bpl + (size_t)NWIN * 8 * 512 * 4);

    k_prep<<<256, 256, 0, stream>>>(kp_desc, Bph, Bpl);
    k_main<<<NWIN * GROUPS, 256, 0, stream>>>(desc_dense, Bph, Bpl, partials);
    k_reduce<<<NWIN * 32, 256, 0, stream>>>(partials, kp_scores, out);
}

// Round 4
// 280.104 us; speedup vs baseline: 2.7610x; 1.9235x over previous
//
#include <hip/hip_runtime.h>
#include <stdint.h>
#include <stddef.h>

#define C_DIM 248
#define N_KP 512
#define HW_PIX 65536
#define NWIN 4
#define NTILE 32           // 512 kp / 16 per tile
#define GROUPS 512         // 128-px groups per window
#define TEMP_SCALE 100.0f

typedef __attribute__((ext_vector_type(8))) short bf16x8;
typedef __attribute__((ext_vector_type(4))) float f32x4;

__device__ __forceinline__ unsigned short f32_bf16(float f) {
    union { float f; uint32_t u; } x; x.f = f;
    uint32_t r = x.u + 0x7FFFu + ((x.u >> 16) & 1u);
    return (unsigned short)(r >> 16);
}
__device__ __forceinline__ float bf16_f32(unsigned short h) {
    union { uint32_t u; float f; } x; x.u = ((uint32_t)h) << 16;
    return x.f;
}

// ---------- Kernel 1: kp desc -> tile-contiguous bf16 hi/lo fragments ----------
// Tile (b,t) = 1024 frags of 16B (16 KB): hi half frag[kk*64 + l4*16 + c15],
// lo half at +512. Frag (c15,l4,kk) = 8 bf16 for k = kk*32 + l4*8 + j, col=t*16+c15.
__global__ __launch_bounds__(256) void k_prep(const float* __restrict__ kd,
                                              bf16x8* __restrict__ Bws) {
    int g = blockIdx.x * 256 + threadIdx.x;       // 65536 threads
    int c15 = g & 15;
    int l4 = (g >> 4) & 3;
    int kk = (g >> 6) & 7;
    int t  = (g >> 9) & 31;
    int b  = g >> 14;
    int col = t * 16 + c15;
    const float* base = kd + (size_t)(2 * b + 1) * C_DIM * N_KP;
    bf16x8 hi, lo;
    #pragma unroll
    for (int j = 0; j < 8; ++j) {
        int c = kk * 32 + l4 * 8 + j;
        float v = (c < C_DIM) ? base[(size_t)c * N_KP + col] : 0.0f;
        unsigned short hb = f32_bf16(v);
        float rlo = v - bf16_f32(hb);
        hi[j] = (short)hb;
        lo[j] = (short)f32_bf16(rlo);
    }
    size_t tb = (size_t)(b * 32 + t) * 1024 + kk * 64 + l4 * 16 + c15;
    Bws[tb] = hi;
    Bws[tb + 512] = lo;
}

// ---------- Kernel 2: A-in-regs (32 px/wave), B LDS-staged, pipelined ----------
// grid: 4 win x 512 groups (128 px); block 256 = 4 waves x 32 px
__global__ __launch_bounds__(256, 2) void k_main(const float* __restrict__ dd,
                                                 const bf16x8* __restrict__ Bws,
                                                 float4* __restrict__ partials) {
    int b = blockIdx.x >> 9;
    int grp = blockIdx.x & 511;
    int tid = threadIdx.x;
    int lane = tid & 63;
    int wave = tid >> 6;
    int l15 = lane & 15;
    int l4 = lane >> 4;
    int pw = grp * 128 + wave * 32;

    __shared__ __align__(16) short Bbuf[3][8192];   // 3 x 16 KB B-tile slots
    __shared__ float4 Wst[4][4][128];               // 8 KB merge buffer

    // ---- A: 32 px x 256 k in regs (hi/lo), fused norm ----
    const float* srcp = dd + (size_t)(2 * b) * C_DIM * HW_PIX;
    bf16x8 aH[2][8], aL[2][8];
    float ss[2] = {0.f, 0.f};
    #pragma unroll
    for (int s = 0; s < 2; ++s) {
        #pragma unroll
        for (int kk = 0; kk < 8; ++kk) {
            #pragma unroll
            for (int j = 0; j < 8; ++j) {
                int c = kk * 32 + l4 * 8 + j;
                float v = (c < C_DIM) ? srcp[(size_t)c * HW_PIX + pw + s * 16 + l15] : 0.0f;
                ss[s] = fmaf(v, v, ss[s]);
                unsigned short hb = f32_bf16(v);
                float rlo = v - bf16_f32(hb);
                aH[s][kk][j] = (short)hb;
                aL[s][kk][j] = (short)f32_bf16(rlo);
            }
        }
        ss[s] += __shfl_xor(ss[s], 16);
        ss[s] += __shfl_xor(ss[s], 32);             // full 248-sum for pixel pw+s*16+l15
    }
    float srow[2][4], uu[2][4], vv[2][4];
    #pragma unroll
    for (int s = 0; s < 2; ++s) {
        #pragma unroll
        for (int r = 0; r < 4; ++r) {
            float ssr = __shfl(ss[s], l4 * 4 + r); // lane i<16 holds pixel pw+s*16+i
            srow[s][r] = TEMP_SCALE / fmaxf(sqrtf(ssr), 1e-12f);
            int pix = pw + s * 16 + l4 * 4 + r;
            uu[s][r] = (float)(pix & 255);
            vv[s][r] = (float)(pix >> 8);
        }
    }

    // ---- stage helper (16 KB tile -> slot): 4 x global_load_lds(16B)/thread ----
    const bf16x8* Btile_base = Bws + (size_t)b * 32 * 1024;
    #define STAGE(slot_, t_)                                                          \
        {                                                                             \
            const bf16x8* src_ = Btile_base + (size_t)(t_) * 1024;                    \
            _Pragma("unroll")                                                         \
            for (int i_ = 0; i_ < 4; ++i_) {                                          \
                __builtin_amdgcn_global_load_lds(                                     \
                    (const __attribute__((address_space(1))) void*)                   \
                        (src_ + (i_ * 4 + wave) * 64 + lane),                         \
                    (__attribute__((address_space(3))) void*)                         \
                        ((char*)&Bbuf[slot_][0] + (i_ * 4 + wave) * 1024),            \
                    16, 0, 0);                                                        \
            }                                                                         \
        }

    STAGE(0, 0)
    STAGE(1, 1)

    for (int t = 0; t < NTILE; ++t) {
        __builtin_amdgcn_s_barrier();               // slot (t+2)%3 free (readers done at t-1)
        if (t < 30) STAGE((t + 2) % 3, t + 2)
        if (t < 30)      asm volatile("s_waitcnt vmcnt(8)" ::: "memory");
        else if (t == 30) asm volatile("s_waitcnt vmcnt(4)" ::: "memory");
        else              asm volatile("s_waitcnt vmcnt(0)" ::: "memory");

        const bf16x8* Bt = (const bf16x8*)&Bbuf[t % 3][0];
        f32x4 acc0 = {0.f, 0.f, 0.f, 0.f};
        f32x4 acc1 = {0.f, 0.f, 0.f, 0.f};
        #pragma unroll
        for (int kk = 0; kk < 8; ++kk) {
            bf16x8 bH = Bt[kk * 64 + lane];
            bf16x8 bL = Bt[512 + kk * 64 + lane];
            acc0 = __builtin_amdgcn_mfma_f32_16x16x32_bf16(aL[0][kk], bH, acc0, 0, 0, 0);
            acc1 = __builtin_amdgcn_mfma_f32_16x16x32_bf16(aL[1][kk], bH, acc1, 0, 0, 0);
            acc0 = __builtin_amdgcn_mfma_f32_16x16x32_bf16(aH[0][kk], bL, acc0, 0, 0, 0);
            acc1 = __builtin_amdgcn_mfma_f32_16x16x32_bf16(aH[1][kk], bL, acc1, 0, 0, 0);
            acc0 = __builtin_amdgcn_mfma_f32_16x16x32_bf16(aH[0][kk], bH, acc0, 0, 0, 0);
            acc1 = __builtin_amdgcn_mfma_f32_16x16x32_bf16(aH[1][kk], bH, acc1, 0, 0, 0);
        }

        // per-lane softmax partial over its 8 pixel rows (kp col = t*16+l15)
        float lg[2][4];
        float m = -3.0e38f;
        #pragma unroll
        for (int r = 0; r < 4; ++r) {
            lg[0][r] = acc0[r] * srow[0][r];
            lg[1][r] = acc1[r] * srow[1][r];
            m = fmaxf(m, fmaxf(lg[0][r], lg[1][r]));
        }
        float d = 0.f, sx = 0.f, sy = 0.f;
        #pragma unroll
        for (int s = 0; s < 2; ++s) {
            #pragma unroll
            for (int r = 0; r < 4; ++r) {
                float e = __expf(lg[s][r] - m);
                d += e;
                sx = fmaf(e, uu[s][r], sx);
                sy = fmaf(e, vv[s][r], sy);
            }
        }
        float4 p; p.x = m; p.y = d; p.z = sx; p.w = sy;
        Wst[wave][l4][(t & 7) * 16 + l15] = p;

        if ((t & 7) == 7) {                          // merge 16 partials -> global
            __syncthreads();
            if (tid < 128) {
                float4 s0 = Wst[0][0][tid];
                float M = s0.x, D = s0.y, SX = s0.z, SY = s0.w;
                #pragma unroll
                for (int sIdx = 1; sIdx < 16; ++sIdx) {
                    float4 q = Wst[sIdx >> 2][sIdx & 3][tid];
                    float Mn = fmaxf(M, q.x);
                    float c1 = __expf(M - Mn);
                    float c2 = __expf(q.x - Mn);
                    D  = D  * c1 + q.y * c2;
                    SX = SX * c1 + q.z * c2;
                    SY = SY * c1 + q.w * c2;
                    M = Mn;
                }
                float4 o; o.x = M; o.y = D; o.z = SX; o.w = SY;
                partials[((size_t)b * GROUPS + grp) * 512 + (t >> 3) * 128 + tid] = o;
            }
            __syncthreads();
        }
    }
    #undef STAGE
}

// ---------- Kernel 3: reduce 512 group-partials per (b,kp) + epilogue ----------
__global__ __launch_bounds__(256) void k_reduce(const float4* __restrict__ partials,
                                                const float* __restrict__ ksc,
                                                float* __restrict__ out) {
    int b = blockIdx.x >> 5;
    int kc = blockIdx.x & 31;
    int tid = threadIdx.x;
    int kpo = tid & 15;
    int gs = tid >> 4;
    int kp = kc * 16 + kpo;

    float M = -1e30f, D = 0.f, SX = 0.f, SY = 0.f;
    for (int g = gs; g < GROUPS; g += 16) {
        float4 p = partials[((size_t)b * GROUPS + g) * 512 + kp];
        float Mn = fmaxf(M, p.x);
        float c1 = __expf(M - Mn);
        float c2 = __expf(p.x - Mn);
        D  = D  * c1 + p.y * c2;
        SX = SX * c1 + p.z * c2;
        SY = SY * c1 + p.w * c2;
        M = Mn;
    }
    __shared__ float4 red[16][16];
    float4 me; me.x = M; me.y = D; me.z = SX; me.w = SY;
    red[gs][kpo] = me;
    __syncthreads();
    if (gs == 0) {
        #pragma unroll
        for (int w = 1; w < 16; ++w) {
            float4 p = red[w][kpo];
            float Mn = fmaxf(M, p.x);
            float c1 = __expf(M - Mn);
            float c2 = __expf(p.x - Mn);
            D  = D  * c1 + p.y * c2;
            SX = SX * c1 + p.z * c2;
            SY = SY * c1 + p.w * c2;
            M = Mn;
        }
        int flat = b * 512 + kp;
        out[flat * 2 + 0] = SX / D;
        out[flat * 2 + 1] = SY / D;
        out[4096 + flat] = ksc[(size_t)(2 * b + 1) * N_KP + kp];
    }
    if (blockIdx.x == 0 && tid < 4) out[6144 + tid] = (float)(2 * tid + 1);
}

extern "C" void kernel_launch(void* const* d_in, const int* in_sizes, int n_in,
                              void* d_out, int out_size, void* d_ws, size_t ws_size,
                              hipStream_t stream) {
    const float* kp_scores  = (const float*)d_in[0];
    const float* kp_desc    = (const float*)d_in[1];
    const float* desc_dense = (const float*)d_in[3];
    float* out = (float*)d_out;

    // ws: Bws 2 MB | partials 16 MB
    bf16x8* Bws = (bf16x8*)d_ws;
    float4* partials = (float4*)((char*)d_ws + (size_t)NWIN * 32 * 1024 * 16);

    k_prep<<<256, 256, 0, stream>>>(kp_desc, Bws);
    k_main<<<NWIN * GROUPS, 256, 0, stream>>>(desc_dense, Bws, partials);
    k_reduce<<<NWIN * 32, 256, 0, stream>>>(partials, kp_scores, out);
}

// Round 5
// 270.435 us; speedup vs baseline: 2.8598x; 1.0358x over previous
//
#include <hip/hip_runtime.h>
#include <stdint.h>
#include <stddef.h>

#define C_DIM 248
#define N_KP 512
#define HW_PIX 65536
#define NWIN 4
#define NTILE 32           // 512 kp / 16 per tile
#define GROUPS 512         // 128-px groups per window
#define TEMP_SCALE 100.0f

typedef __attribute__((ext_vector_type(8))) short bf16x8;
typedef __attribute__((ext_vector_type(4))) float f32x4;

__device__ __forceinline__ unsigned short f32_bf16(float f) {
    union { float f; uint32_t u; } x; x.f = f;
    uint32_t r = x.u + 0x7FFFu + ((x.u >> 16) & 1u);
    return (unsigned short)(r >> 16);
}
__device__ __forceinline__ float bf16_f32(unsigned short h) {
    union { uint32_t u; float f; } x; x.u = ((uint32_t)h) << 16;
    return x.f;
}

// ---------- Kernel 1: kp desc -> tile-contiguous bf16 hi/lo fragments ----------
// Tile (b,t) = 1024 frags of 16B (16 KB): hi half frag[kk*64 + l4*16 + c15],
// lo half at +512. Frag (c15,l4,kk) = 8 bf16 for k = kk*32 + l4*8 + j, col=t*16+c15.
__global__ __launch_bounds__(256) void k_prep(const float* __restrict__ kd,
                                              bf16x8* __restrict__ Bws) {
    int g = blockIdx.x * 256 + threadIdx.x;       // 65536 threads
    int c15 = g & 15;
    int l4 = (g >> 4) & 3;
    int kk = (g >> 6) & 7;
    int t  = (g >> 9) & 31;
    int b  = g >> 14;
    int col = t * 16 + c15;
    const float* base = kd + (size_t)(2 * b + 1) * C_DIM * N_KP;
    bf16x8 hi, lo;
    #pragma unroll
    for (int j = 0; j < 8; ++j) {
        int c = kk * 32 + l4 * 8 + j;
        float v = (c < C_DIM) ? base[(size_t)c * N_KP + col] : 0.0f;
        unsigned short hb = f32_bf16(v);
        float rlo = v - bf16_f32(hb);
        hi[j] = (short)hb;
        lo[j] = (short)f32_bf16(rlo);
    }
    size_t tb = (size_t)(b * 32 + t) * 1024 + kk * 64 + l4 * 16 + c15;
    Bws[tb] = hi;
    Bws[tb + 512] = lo;
}

// ---------- Kernel 2: A-in-regs (32 px/wave), B LDS-staged, race-free pipeline ----------
// grid: 4 win x 512 groups (128 px); block 256 = 4 waves x 32 px
__global__ __launch_bounds__(256, 2) void k_main(const float* __restrict__ dd,
                                                 const bf16x8* __restrict__ Bws,
                                                 float4* __restrict__ partials) {
    int b = blockIdx.x >> 9;
    int grp = blockIdx.x & 511;
    int tid = threadIdx.x;
    int lane = tid & 63;
    int wave = tid >> 6;
    int l15 = lane & 15;
    int l4 = lane >> 4;
    int pw = grp * 128 + wave * 32;

    __shared__ __align__(16) short Bbuf[3][8192];   // 3 x 16 KB B-tile slots
    __shared__ float4 Wst[4][4][128];               // 8 KB merge buffer

    // ---- stage helper (16 KB tile -> slot): 4 x global_load_lds(16B)/thread ----
    const bf16x8* Btile_base = Bws + (size_t)b * 32 * 1024;
    #define STAGE(slot_, t_)                                                          \
        {                                                                             \
            const bf16x8* src_ = Btile_base + (size_t)(t_) * 1024;                    \
            _Pragma("unroll")                                                         \
            for (int i_ = 0; i_ < 4; ++i_) {                                          \
                __builtin_amdgcn_global_load_lds(                                     \
                    (const __attribute__((address_space(1))) void*)                   \
                        (src_ + (i_ * 4 + wave) * 64 + lane),                         \
                    (__attribute__((address_space(3))) void*)                         \
                        ((char*)&Bbuf[slot_][0] + (i_ * 4 + wave) * 1024),            \
                    16, 0, 0);                                                        \
            }                                                                         \
        }

    STAGE(0, 0)
    STAGE(1, 1)

    // ---- A: 32 px x 256 k in regs (hi/lo), fused norm (overlaps stage latency) ----
    const float* srcp = dd + (size_t)(2 * b) * C_DIM * HW_PIX;
    bf16x8 aH[2][8], aL[2][8];
    float ss[2] = {0.f, 0.f};
    #pragma unroll
    for (int s = 0; s < 2; ++s) {
        #pragma unroll
        for (int kk = 0; kk < 8; ++kk) {
            #pragma unroll
            for (int j = 0; j < 8; ++j) {
                int c = kk * 32 + l4 * 8 + j;
                float v = (c < C_DIM) ? srcp[(size_t)c * HW_PIX + pw + s * 16 + l15] : 0.0f;
                ss[s] = fmaf(v, v, ss[s]);
                unsigned short hb = f32_bf16(v);
                float rlo = v - bf16_f32(hb);
                aH[s][kk][j] = (short)hb;
                aL[s][kk][j] = (short)f32_bf16(rlo);
            }
        }
        ss[s] += __shfl_xor(ss[s], 16);
        ss[s] += __shfl_xor(ss[s], 32);             // full 248-sum for pixel pw+s*16+l15
    }
    float srow[2][4], uu[2][4], vv[2][4];
    #pragma unroll
    for (int s = 0; s < 2; ++s) {
        #pragma unroll
        for (int r = 0; r < 4; ++r) {
            float ssr = __shfl(ss[s], l4 * 4 + r); // lane i<16 holds pixel pw+s*16+i
            srow[s][r] = TEMP_SCALE / fmaxf(sqrtf(ssr), 1e-12f);
            int pix = pw + s * 16 + l4 * 4 + r;
            uu[s][r] = (float)(pix & 255);
            vv[s][r] = (float)(pix >> 8);
        }
    }

    for (int t = 0; t < NTILE; ++t) {
        // own stage(t) loads complete BEFORE the barrier -> barrier certifies
        // every wave's slot-t bytes landed (race-free counted-vmcnt pattern)
        if (t < NTILE - 1) asm volatile("s_waitcnt vmcnt(4)" ::: "memory");
        else               asm volatile("s_waitcnt vmcnt(0)" ::: "memory");
        __builtin_amdgcn_s_barrier();
        if (t < NTILE - 2) STAGE((t + 2) % 3, t + 2)  // slot free: readers finished t-1

        const bf16x8* Bt = (const bf16x8*)&Bbuf[t % 3][0];
        f32x4 acc[2][3];
        #pragma unroll
        for (int s = 0; s < 2; ++s)
            #pragma unroll
            for (int p = 0; p < 3; ++p) acc[s][p] = (f32x4){0.f, 0.f, 0.f, 0.f};

        __builtin_amdgcn_s_setprio(1);
        #pragma unroll
        for (int kk = 0; kk < 8; ++kk) {
            bf16x8 bH = Bt[kk * 64 + lane];
            bf16x8 bL = Bt[512 + kk * 64 + lane];
            acc[0][0] = __builtin_amdgcn_mfma_f32_16x16x32_bf16(aH[0][kk], bH, acc[0][0], 0, 0, 0);
            acc[1][0] = __builtin_amdgcn_mfma_f32_16x16x32_bf16(aH[1][kk], bH, acc[1][0], 0, 0, 0);
            acc[0][1] = __builtin_amdgcn_mfma_f32_16x16x32_bf16(aH[0][kk], bL, acc[0][1], 0, 0, 0);
            acc[1][1] = __builtin_amdgcn_mfma_f32_16x16x32_bf16(aH[1][kk], bL, acc[1][1], 0, 0, 0);
            acc[0][2] = __builtin_amdgcn_mfma_f32_16x16x32_bf16(aL[0][kk], bH, acc[0][2], 0, 0, 0);
            acc[1][2] = __builtin_amdgcn_mfma_f32_16x16x32_bf16(aL[1][kk], bH, acc[1][2], 0, 0, 0);
        }
        __builtin_amdgcn_s_setprio(0);

        // per-lane softmax partial over its 8 pixel rows (kp col = t*16+l15)
        float lg[2][4];
        float m = -3.0e38f;
        #pragma unroll
        for (int r = 0; r < 4; ++r) {
            lg[0][r] = (acc[0][0][r] + acc[0][1][r] + acc[0][2][r]) * srow[0][r];
            lg[1][r] = (acc[1][0][r] + acc[1][1][r] + acc[1][2][r]) * srow[1][r];
            m = fmaxf(m, fmaxf(lg[0][r], lg[1][r]));
        }
        float d = 0.f, sx = 0.f, sy = 0.f;
        #pragma unroll
        for (int s = 0; s < 2; ++s) {
            #pragma unroll
            for (int r = 0; r < 4; ++r) {
                float e = __expf(lg[s][r] - m);
                d += e;
                sx = fmaf(e, uu[s][r], sx);
                sy = fmaf(e, vv[s][r], sy);
            }
        }
        float4 p; p.x = m; p.y = d; p.z = sx; p.w = sy;
        Wst[wave][l4][(t & 7) * 16 + l15] = p;

        if ((t & 7) == 7) {                          // merge 16 partials -> global
            __syncthreads();
            if (tid < 128) {
                float4 s0 = Wst[0][0][tid];
                float M = s0.x, D = s0.y, SX = s0.z, SY = s0.w;
                #pragma unroll
                for (int sIdx = 1; sIdx < 16; ++sIdx) {
                    float4 q = Wst[sIdx >> 2][sIdx & 3][tid];
                    float Mn = fmaxf(M, q.x);
                    float c1 = __expf(M - Mn);
                    float c2 = __expf(q.x - Mn);
                    D  = D  * c1 + q.y * c2;
                    SX = SX * c1 + q.z * c2;
                    SY = SY * c1 + q.w * c2;
                    M = Mn;
                }
                float4 o; o.x = M; o.y = D; o.z = SX; o.w = SY;
                partials[((size_t)b * GROUPS + grp) * 512 + (t >> 3) * 128 + tid] = o;
            }
            __syncthreads();
        }
    }
    #undef STAGE
}

// ---------- Kernel 3: reduce 512 group-partials per (b,kp) + epilogue ----------
__global__ __launch_bounds__(256) void k_reduce(const float4* __restrict__ partials,
                                                const float* __restrict__ ksc,
                                                float* __restrict__ out) {
    int b = blockIdx.x >> 5;
    int kc = blockIdx.x & 31;
    int tid = threadIdx.x;
    int kpo = tid & 15;
    int gs = tid >> 4;
    int kp = kc * 16 + kpo;

    float M = -1e30f, D = 0.f, SX = 0.f, SY = 0.f;
    for (int g = gs; g < GROUPS; g += 16) {
        float4 p = partials[((size_t)b * GROUPS + g) * 512 + kp];
        float Mn = fmaxf(M, p.x);
        float c1 = __expf(M - Mn);
        float c2 = __expf(p.x - Mn);
        D  = D  * c1 + p.y * c2;
        SX = SX * c1 + p.z * c2;
        SY = SY * c1 + p.w * c2;
        M = Mn;
    }
    __shared__ float4 red[16][16];
    float4 me; me.x = M; me.y = D; me.z = SX; me.w = SY;
    red[gs][kpo] = me;
    __syncthreads();
    if (gs == 0) {
        #pragma unroll
        for (int w = 1; w < 16; ++w) {
            float4 p = red[w][kpo];
            float Mn = fmaxf(M, p.x);
            float c1 = __expf(M - Mn);
            float c2 = __expf(p.x - Mn);
            D  = D  * c1 + p.y * c2;
            SX = SX * c1 + p.z * c2;
            SY = SY * c1 + p.w * c2;
            M = Mn;
        }
        int flat = b * 512 + kp;
        out[flat * 2 + 0] = SX / D;
        out[flat * 2 + 1] = SY / D;
        out[4096 + flat] = ksc[(size_t)(2 * b + 1) * N_KP + kp];
    }
    if (blockIdx.x == 0 && tid < 4) out[6144 + tid] = (float)(2 * tid + 1);
}

extern "C" void kernel_launch(void* const* d_in, const int* in_sizes, int n_in,
                              void* d_out, int out_size, void* d_ws, size_t ws_size,
                              hipStream_t stream) {
    const float* kp_scores  = (const float*)d_in[0];
    const float* kp_desc    = (const float*)d_in[1];
    const float* desc_dense = (const float*)d_in[3];
    float* out = (float*)d_out;

    // ws: Bws 2 MB | partials 16 MB
    bf16x8* Bws = (bf16x8*)d_ws;
    float4* partials = (float4*)((char*)d_ws + (size_t)NWIN * 32 * 1024 * 16);

    k_prep<<<256, 256, 0, stream>>>(kp_desc, Bws);
    k_main<<<NWIN * GROUPS, 256, 0, stream>>>(desc_dense, Bws, partials);
    k_reduce<<<NWIN * 32, 256, 0, stream>>>(partials, kp_scores, out);
}